// Round 1
// baseline (81.724 us; speedup 1.0000x reference)
//
#include <hip/hip_runtime.h>

#define N_TOKENS 8192
#define D_MODEL  1024
#define E_NUM    8
#define SCAN_THREADS 1024
#define TPT (N_TOKENS / SCAN_THREADS)   // 8 tokens per thread
#define ROWS_PER_BLOCK 4

// ---------------------------------------------------------------------------
// Kernel 1: routing decision + per-expert prefix-sum + inverse map.
// Single block of 1024 threads; thread t owns tokens [t*8, t*8+8).
// Per-expert counts packed as 16-bit fields in two u64s (loads <= 8192 fits).
// ---------------------------------------------------------------------------
__global__ __launch_bounds__(SCAN_THREADS)
void route_kernel(const float* __restrict__ gates,
                  int* __restrict__ rows,      // [E_NUM * N_TOKENS] inverse map
                  int* __restrict__ loads_i,   // [E_NUM]
                  float* __restrict__ loads_f) // d_out tail
{
    const int tid = threadIdx.x;
    __shared__ unsigned long long s0[SCAN_THREADS];
    __shared__ unsigned long long s1[SCAN_THREADS];

    unsigned char masks[TPT];
    unsigned long long c0 = 0ull, c1 = 0ull;  // experts 0..3 / 4..7, 16-bit fields
    const int t0 = tid * TPT;

#pragma unroll
    for (int k = 0; k < TPT; ++k) {
        const float4 g0 = *reinterpret_cast<const float4*>(gates + (size_t)(t0 + k) * E_NUM);
        const float4 g1 = *reinterpret_cast<const float4*>(gates + (size_t)(t0 + k) * E_NUM + 4);
        unsigned m = 0;
        m |= (g0.x > 0.0f) ? 1u   : 0u;
        m |= (g0.y > 0.0f) ? 2u   : 0u;
        m |= (g0.z > 0.0f) ? 4u   : 0u;
        m |= (g0.w > 0.0f) ? 8u   : 0u;
        m |= (g1.x > 0.0f) ? 16u  : 0u;
        m |= (g1.y > 0.0f) ? 32u  : 0u;
        m |= (g1.z > 0.0f) ? 64u  : 0u;
        m |= (g1.w > 0.0f) ? 128u : 0u;
        if (m == 0u) m = 1u;   // residual -> expert 0
        masks[k] = (unsigned char)m;
#pragma unroll
        for (int e = 0; e < 4; ++e) {
            c0 += (unsigned long long)((m >> e) & 1u) << (16 * e);
            c1 += (unsigned long long)((m >> (e + 4)) & 1u) << (16 * e);
        }
    }

    // Hillis-Steele inclusive scan over the 1024 per-thread packed counts.
    unsigned long long v0 = c0, v1 = c1;
    s0[tid] = v0; s1[tid] = v1;
    __syncthreads();
    for (int off = 1; off < SCAN_THREADS; off <<= 1) {
        unsigned long long a0 = 0ull, a1 = 0ull;
        if (tid >= off) { a0 = s0[tid - off]; a1 = s1[tid - off]; }
        __syncthreads();
        v0 += a0; v1 += a1;
        s0[tid] = v0; s1[tid] = v1;
        __syncthreads();
    }

    // Exclusive per-expert base offsets for this thread.
    const unsigned long long e0 = v0 - c0, e1 = v1 - c1;
    int offs[E_NUM];
#pragma unroll
    for (int e = 0; e < 4; ++e) {
        offs[e]     = (int)((e0 >> (16 * e)) & 0xFFFFull);
        offs[e + 4] = (int)((e1 >> (16 * e)) & 0xFFFFull);
    }

    // Scatter inverse map: rows[e][r] = token index (ascending token order).
#pragma unroll
    for (int k = 0; k < TPT; ++k) {
        const unsigned m = masks[k];
        const int token = t0 + k;
#pragma unroll
        for (int e = 0; e < E_NUM; ++e) {
            if (m & (1u << e)) {
                rows[e * N_TOKENS + offs[e]] = token;
                offs[e]++;
            }
        }
    }

    // Last thread holds the inclusive totals == loads.
    if (tid == SCAN_THREADS - 1) {
#pragma unroll
        for (int e = 0; e < 4; ++e) {
            const int l0 = (int)((v0 >> (16 * e)) & 0xFFFFull);
            const int l1 = (int)((v1 >> (16 * e)) & 0xFFFFull);
            loads_i[e]     = l0;
            loads_i[e + 4] = l1;
            loads_f[e]     = (float)l0;
            loads_f[e + 4] = (float)l1;
        }
    }
}

// ---------------------------------------------------------------------------
// Kernel 2: write the full (E, N, D) output. Each block handles 4 rows;
// each thread stores one float4 per row (256 * 4 = 1024 floats = D).
// Row (e, r): copy in_flow[rows[e][r]] if r < loads[e], else zeros.
// ---------------------------------------------------------------------------
__global__ __launch_bounds__(256)
void scatter_kernel(const float* __restrict__ in_flow,
                    const int* __restrict__ rows,
                    const int* __restrict__ loads_i,
                    float* __restrict__ out)
{
    const int tid = threadIdx.x;
    const long long row0 = (long long)blockIdx.x * ROWS_PER_BLOCK;

#pragma unroll
    for (int j = 0; j < ROWS_PER_BLOCK; ++j) {
        const long long row = row0 + j;              // flat (e, r)
        const int e = (int)(row >> 13);              // N_TOKENS = 8192
        const int r = (int)(row & (N_TOKENS - 1));
        float4 val;
        if (r < loads_i[e]) {
            const int t = rows[row];
            val = *reinterpret_cast<const float4*>(
                in_flow + (size_t)t * D_MODEL + (size_t)tid * 4);
        } else {
            val = make_float4(0.0f, 0.0f, 0.0f, 0.0f);
        }
        *reinterpret_cast<float4*>(out + row * D_MODEL + (size_t)tid * 4) = val;
    }
}

extern "C" void kernel_launch(void* const* d_in, const int* in_sizes, int n_in,
                              void* d_out, int out_size, void* d_ws, size_t ws_size,
                              hipStream_t stream) {
    const float* in_flow = (const float*)d_in[0];   // (8192, 1024) f32
    const float* gates   = (const float*)d_in[1];   // (8192, 8) f32
    float* out = (float*)d_out;                     // 8*8192*1024 + 8 floats

    int* rows    = (int*)d_ws;                      // E*N ints = 256 KB
    int* loads_i = rows + E_NUM * N_TOKENS;         // 8 ints
    float* loads_f = out + (size_t)E_NUM * N_TOKENS * D_MODEL;

    route_kernel<<<1, SCAN_THREADS, 0, stream>>>(gates, rows, loads_i, loads_f);

    const int n_rows = E_NUM * N_TOKENS;            // 65536
    scatter_kernel<<<n_rows / ROWS_PER_BLOCK, 256, 0, stream>>>(
        in_flow, rows, loads_i, out);
}